// Round 8
// baseline (220.320 us; speedup 1.0000x reference)
//
#include <hip/hip_runtime.h>
#include <stdint.h>

// Problem constants
#define T_   2048
#define NH   16
#define HD   64
#define NBH  64     // B*H
#define CDIM 1024
#define MROWS 8192  // B*T

typedef __attribute__((ext_vector_type(8))) short short8;
typedef __attribute__((ext_vector_type(4))) float f32x4;
typedef __attribute__((ext_vector_type(16))) float f32x16;
typedef __attribute__((ext_vector_type(2))) unsigned int uint32x2;

#define LOG2E 1.44269504088896340736f

static __device__ __forceinline__ uint16_t f2bf(float f) {
  uint32_t u = __float_as_uint(f);
  return (uint16_t)((u + 0x7FFFu + ((u >> 16) & 1u)) >> 16);
}

static __device__ __forceinline__ void async16(const void* g, void* l) {
  __builtin_amdgcn_global_load_lds(
      (const __attribute__((address_space(1))) uint32_t*)g,
      (__attribute__((address_space(3))) uint32_t*)l, 16, 0, 0);
}

// permlane32_swap builtin: returns {vdst_new, vsrc_new}
static __device__ __forceinline__ uint32x2 plswap(uint32_t a, uint32_t b) {
  return __builtin_amdgcn_permlane32_swap(a, b, false, false);
}
static __device__ __forceinline__ float halves_max(float x) {
  uint32x2 r = plswap(__float_as_uint(x), __float_as_uint(x));
  return fmaxf(__uint_as_float(r[0]), __uint_as_float(r[1]));
}
static __device__ __forceinline__ float halves_sum(float x) {
  uint32x2 r = plswap(__float_as_uint(x), __float_as_uint(x));
  return __uint_as_float(r[0]) + __uint_as_float(r[1]);
}
static __device__ __forceinline__ uint32_t pkbf(float lo, float hi) {
  uint32_t r;
  asm("v_cvt_pk_bf16_f32 %0, %1, %2" : "=v"(r) : "v"(lo), "v"(hi));
  return r;
}
static __device__ __forceinline__ float tmax32(const f32x16& a, const f32x16& b) {
  float t[16];
#pragma unroll
  for (int r = 0; r < 16; ++r) t[r] = fmaxf(a[r], b[r]);
#pragma unroll
  for (int s = 8; s >= 1; s >>= 1)
#pragma unroll
    for (int r = 0; r < s; ++r) t[r] = fmaxf(t[r], t[r + s]);
  return t[0];
}
static __device__ __forceinline__ float tsum32(const f32x16& a, const f32x16& b) {
  float t[16];
#pragma unroll
  for (int r = 0; r < 16; ++r) t[r] = a[r] + b[r];
#pragma unroll
  for (int s = 8; s >= 1; s >>= 1)
#pragma unroll
    for (int r = 0; r < s; ++r) t[r] += t[r + s];
  return t[0];
}

// ---------------- fp32 -> bf16 convert ----------------
__global__ __launch_bounds__(256) void cvt_f32_bf16(const float* __restrict__ in,
                                                    uint16_t* __restrict__ out, int n) {
  int i = (blockIdx.x * 256 + threadIdx.x) * 4;
  int stride = gridDim.x * 256 * 4;
  for (; i < n; i += stride) {
    float4 v = *(const float4*)(in + i);
    ushort4 o;
    o.x = f2bf(v.x); o.y = f2bf(v.y); o.z = f2bf(v.z); o.w = f2bf(v.w);
    *(ushort4*)(out + i) = o;
  }
}

// ---------------- QKV GEMM v2: 256x256, BK=32, 8 waves, ring-3 LDS ----------
// Per K-tile t: compute from buf t%3 (landed), stage tile t+2 into buf
// (t-1)%3 (freed by the boundary barrier). 2 phases per tile, each:
//   {stage 2 gload_lds; ds_read 4-8 b128; s_barrier; lgkmcnt(0)+sched_barrier;
//    setprio(1); 16 MFMA; setprio(0); s_barrier}
// Boundary: counted vmcnt(4) (tile t+1's 4 loads landed, t+2's still in
// flight; in-order retirement) — vmcnt(0) only at t=30. Raw s_barrier
// throughout (never __syncthreads, which force-drains vmcnt).
// Bank swizzle: read chunk ^= (row>>1)&3 (2 lanes/16B-slot = free); source
// pre-swizzled: csrc = (lane&3) ^ ((lane>>3)&3); LDS dest linear (lane*16B
// == (lane>>2)*row + (lane&3)*chunk for our 16-row/1KB instr blocks).
// XCD swizzle A-local: 48 contiguous wgid/XCD -> 4 bx x 12 by (A panel 2MB).
__global__ __launch_bounds__(512, 2) void gemm256v2(
    const uint16_t* __restrict__ A, const uint16_t* __restrict__ Bt,
    uint16_t* __restrict__ Qo, uint16_t* __restrict__ Ko, uint16_t* __restrict__ Vo,
    const int* __restrict__ perm) {
  __shared__ __attribute__((aligned(16))) uint16_t lA[3][256 * 32];  // 48KB
  __shared__ __attribute__((aligned(16))) uint16_t lB[3][256 * 32];  // 48KB

  const int orig = blockIdx.x;
  const int wgid = (orig & 7) * 48 + (orig >> 3);   // bijective (384%8==0)
  const int bx = wgid / 12, by = wgid % 12;
  const int mbase = bx * 256, nbase = by * 256;

  const int t = threadIdx.x;
  const int lane = t & 63, wv = t >> 6;
  const int wm = wv & 1, wn = wv >> 1;     // wave grid 2M x 4N, wave tile 128x64
  const int gq = lane >> 4, lc = lane & 15;

  const int srow = lane >> 2;                        // 0..15 within 16-row block
  const int csrc = (lane & 3) ^ ((lane >> 3) & 3);   // pre-swizzled source chunk
  const int rx = (lc >> 1) & 3;                      // read-side chunk XOR

  f32x4 acc[8][4];
#pragma unroll
  for (int i = 0; i < 8; ++i)
#pragma unroll
    for (int j = 0; j < 4; ++j) acc[i][j] = (f32x4){0.f, 0.f, 0.f, 0.f};

  // stage one operand's 256x32 K-tile: instr i covers rows 16i..16i+15 (1KB)
#define STAGE_A(kt, buf)                                                        \
  {                                                                             \
    _Pragma("unroll")                                                           \
    for (int j = 0; j < 2; ++j) {                                               \
      int i_ = 2 * wv + j;                                                      \
      async16(A + ((size_t)(mbase + 16 * i_ + srow) * CDIM + (kt) * 32 + csrc * 8), \
              (char*)&lA[buf][0] + i_ * 1024);                                  \
    }                                                                           \
  }
#define STAGE_B(kt, buf)                                                        \
  {                                                                             \
    _Pragma("unroll")                                                           \
    for (int j = 0; j < 2; ++j) {                                               \
      int i_ = 2 * wv + j;                                                      \
      async16(Bt + ((size_t)(nbase + 16 * i_ + srow) * CDIM + (kt) * 32 + csrc * 8), \
              (char*)&lB[buf][0] + i_ * 1024);                                  \
    }                                                                           \
  }

  // prologue: tiles 0,1 -> bufs 0,1; wait tile 0 landed (4 newest outstanding)
  STAGE_A(0, 0); STAGE_B(0, 0);
  STAGE_A(1, 1); STAGE_B(1, 1);
  asm volatile("s_waitcnt vmcnt(4)" ::: "memory");
  __builtin_amdgcn_s_barrier();

  int bt = 0;
  for (int kt = 0; kt < 32; ++kt) {
    const uint16_t* pa = &lA[bt][0];
    const uint16_t* pb = &lB[bt][0];
    const int ks = kt + 2;
    const int bs = (bt + 2 >= 3) ? bt - 1 : bt + 2;  // (bt+2)%3

    // ---- phase 0: stage A(kt+2); read B(all) + A(mi0-3); MFMA q01 ----
    if (ks < 32) STAGE_A(ks, bs);
    short8 bfr[4], af[4];
#pragma unroll
    for (int ni = 0; ni < 4; ++ni)
      bfr[ni] = *(const short8*)&pb[(wn * 64 + ni * 16 + lc) * 32 + ((gq ^ rx) * 8)];
#pragma unroll
    for (int mi = 0; mi < 4; ++mi)
      af[mi] = *(const short8*)&pa[(wm * 128 + mi * 16 + lc) * 32 + ((gq ^ rx) * 8)];
    __builtin_amdgcn_s_barrier();
    asm volatile("s_waitcnt lgkmcnt(0)" ::: "memory");
    __builtin_amdgcn_sched_barrier(0);
    __builtin_amdgcn_s_setprio(1);
#pragma unroll
    for (int mi = 0; mi < 4; ++mi)
#pragma unroll
      for (int ni = 0; ni < 4; ++ni)
        acc[mi][ni] = __builtin_amdgcn_mfma_f32_16x16x32_bf16(af[mi], bfr[ni], acc[mi][ni], 0, 0, 0);
    __builtin_amdgcn_s_setprio(0);
    __builtin_amdgcn_s_barrier();

    // ---- phase 1: stage B(kt+2); read A(mi4-7); MFMA q23 ----
    if (ks < 32) STAGE_B(ks, bs);
    short8 af2[4];
#pragma unroll
    for (int mi = 0; mi < 4; ++mi)
      af2[mi] = *(const short8*)&pa[(wm * 128 + (mi + 4) * 16 + lc) * 32 + ((gq ^ rx) * 8)];
    __builtin_amdgcn_s_barrier();
    asm volatile("s_waitcnt lgkmcnt(0)" ::: "memory");
    __builtin_amdgcn_sched_barrier(0);
    __builtin_amdgcn_s_setprio(1);
#pragma unroll
    for (int mi = 0; mi < 4; ++mi)
#pragma unroll
      for (int ni = 0; ni < 4; ++ni)
        acc[mi + 4][ni] = __builtin_amdgcn_mfma_f32_16x16x32_bf16(af2[mi], bfr[ni], acc[mi + 4][ni], 0, 0, 0);
    __builtin_amdgcn_s_setprio(0);

    // ---- boundary: tile kt+1 must be landed; keep kt+2's loads in flight ----
    if (kt < 30) {
      asm volatile("s_waitcnt vmcnt(4)" ::: "memory");
    } else {
      asm volatile("s_waitcnt vmcnt(0)" ::: "memory");
    }
    __builtin_amdgcn_s_barrier();
    bt = (bt + 1 == 3) ? 0 : bt + 1;
  }

  // ---- scatter epilogue: Q (pre-scaled), K/V permuted ----
#pragma unroll
  for (int mi = 0; mi < 8; ++mi) {
#pragma unroll
    for (int rr = 0; rr < 4; ++rr) {
      int m = mbase + wm * 128 + mi * 16 + 4 * gq + rr;
      int b = m >> 11, s = m & 2047;
      int p = perm[s];
#pragma unroll
      for (int ni = 0; ni < 4; ++ni) {
        int col = nbase + wn * 64 + ni * 16 + lc;
        int typ = col >> 10, cc = col & 1023;
        int h = cc >> 6, d = cc & 63;
        int bh = b * 16 + h;
        float v = acc[mi][ni][rr];
        if (typ == 0)
          Qo[((size_t)bh * T_ + s) * HD + d] = f2bf(v * (0.125f * LOG2E));
        else if (typ == 1)
          Ko[((size_t)bh * T_ + p) * HD + d] = f2bf(v);
        else
          Vo[((size_t)bh * T_ + p) * HD + d] = f2bf(v);
      }
    }
  }
#undef STAGE_A
#undef STAGE_B
}

// ---------------- GEMM: C[M,N] = A[M,K] * Bt[N,K]^T (proj only) -------------
__global__ __launch_bounds__(256) void gemm_bt(
    const uint16_t* __restrict__ A, const uint16_t* __restrict__ Bt,
    float* __restrict__ Cout, const float* __restrict__ bias, int N) {
  __shared__ uint16_t lA[128 * 32];
  __shared__ uint16_t lB[128 * 32];

  const int t = threadIdx.x;
  const int lane = t & 63, wv = t >> 6;
  const int gq = lane >> 4, lc = lane & 15;
  const int mbase = blockIdx.x * 128;
  const int nbase = blockIdx.y * 128;
  const int wr = (wv >> 1) * 64, wc = (wv & 1) * 64;

  f32x4 acc[4][4];
#pragma unroll
  for (int i = 0; i < 4; ++i)
#pragma unroll
    for (int j = 0; j < 4; ++j) acc[i][j] = (f32x4){0.f, 0.f, 0.f, 0.f};

  const int srow = t >> 2;            // 0..63 (per issue)
  const int scb  = (t & 3) * 16;      // byte-in-row 0/16/32/48

  for (int kt = 0; kt < 32; ++kt) {
    const char* baseA = (const char*)A + ((size_t)mbase * CDIM + kt * 32) * 2;
    const char* baseB = (const char*)Bt + ((size_t)nbase * CDIM + kt * 32) * 2;
#pragma unroll
    for (int j = 0; j < 2; ++j) {
      int row = j * 64 + srow;
      async16(baseA + (size_t)row * (CDIM * 2) + scb, (char*)lA + j * 4096 + wv * 1024);
    }
#pragma unroll
    for (int j = 0; j < 2; ++j) {
      int row = j * 64 + srow;
      async16(baseB + (size_t)row * (CDIM * 2) + scb, (char*)lB + j * 4096 + wv * 1024);
    }
    asm volatile("s_waitcnt vmcnt(0)" ::: "memory");
    __syncthreads();

    short8 af[4], bfr[4];
#pragma unroll
    for (int mi = 0; mi < 4; ++mi)
      af[mi] = *(const short8*)&lA[(wr + mi * 16 + lc) * 32 + 8 * gq];
#pragma unroll
    for (int ni = 0; ni < 4; ++ni)
      bfr[ni] = *(const short8*)&lB[(wc + ni * 16 + lc) * 32 + 8 * gq];
#pragma unroll
    for (int mi = 0; mi < 4; ++mi)
#pragma unroll
      for (int ni = 0; ni < 4; ++ni)
        acc[mi][ni] = __builtin_amdgcn_mfma_f32_16x16x32_bf16(af[mi], bfr[ni], acc[mi][ni], 0, 0, 0);
    __syncthreads();
  }

#pragma unroll
  for (int mi = 0; mi < 4; ++mi) {
    int row = mbase + wr + mi * 16 + 4 * gq;
#pragma unroll
    for (int ni = 0; ni < 4; ++ni) {
      int col = nbase + wc + ni * 16 + lc;
      float bv = bias[col];
#pragma unroll
      for (int r = 0; r < 4; ++r)
        Cout[(size_t)(row + r) * N + col] = acc[mi][ni][r] + bv;
    }
  }
}

// ---------------- V transpose: [bh][p][d] -> [bh][d][p] ----------------
__global__ __launch_bounds__(256) void transpose_v(const uint16_t* __restrict__ Vp,
                                                   uint16_t* __restrict__ Vt) {
  __shared__ uint16_t tile[64][72];
  const int pb = blockIdx.x * 64;
  const int bh = blockIdx.y;
  const int t = threadIdx.x;
  const uint16_t* src = Vp + (size_t)bh * T_ * HD + (size_t)pb * HD;
#pragma unroll
  for (int it = 0; it < 2; ++it) {
    int lin = it * 256 + t;
    int row = lin >> 3, col = (lin & 7) * 8;
    short8 v = *(const short8*)(src + row * HD + col);
    *(short8*)&tile[row][col] = v;
  }
  __syncthreads();
  uint16_t* dst = Vt + (size_t)bh * HD * T_;
#pragma unroll
  for (int it = 0; it < 2; ++it) {
    int lin = it * 256 + t;
    int d = lin >> 3, ps = (lin & 7) * 8;
    short8 v;
#pragma unroll
    for (int j = 0; j < 8; ++j) v[j] = (short)tile[ps + j][d];
    *(short8*)(dst + (size_t)d * T_ + pb + ps) = v;
  }
}

// ---------------- causal flash attention, swapped-operand 32x32 ----------------
__global__ __launch_bounds__(256, 4) void attn_kernel(
    const uint16_t* __restrict__ Q, const uint16_t* __restrict__ Kp,
    const uint16_t* __restrict__ Vt, uint16_t* __restrict__ Y) {
  __shared__ __attribute__((aligned(16))) uint16_t lK[2][64 * 64];
  __shared__ __attribute__((aligned(16))) uint16_t lV[2][64 * 64];

  const int bh = blockIdx.x;
  const int b = bh >> 4, h = bh & 15;
  const int qb = (gridDim.y - 1 - blockIdx.y) * 128;  // heavy blocks first
  const int t = threadIdx.x;
  const int lane = t & 63, wv = t >> 6;
  const int l31 = lane & 31, hi = lane >> 5;
  const int qw = qb + 32 * wv;
  const int qg = qw + l31;

  const uint16_t* Qb = Q + ((size_t)bh * T_ + qw) * HD;
  const uint16_t* Kb = Kp + (size_t)bh * T_ * HD;
  const uint16_t* Vb = Vt + (size_t)bh * HD * T_;

  const int srow8 = lane >> 3;               // 0..7
  const int schunk = (lane & 7) ^ srow8;     // swizzled source chunk (16B units)

  short8 qf[4];
#pragma unroll
  for (int kc = 0; kc < 4; ++kc)
    qf[kc] = *(const short8*)(Qb + (size_t)l31 * HD + 16 * kc + 8 * hi);

  f32x16 ot[2];
#pragma unroll
  for (int dt = 0; dt < 2; ++dt)
#pragma unroll
    for (int r = 0; r < 16; ++r) ot[dt][r] = 0.f;
  float mrun = -__builtin_inff();
  float lrun = 0.f;

  const int nkt_blk = (qb >> 6) + 2;
  const int myKt = qw >> 6;

  {
    const int p0 = 0;
#pragma unroll
    for (int j = 0; j < 2; ++j) {
      int i = 2 * wv + j;
      async16(Kb + (size_t)(p0 + 8 * i + srow8) * HD + schunk * 8,
              (char*)&lK[0][0] + i * 1024);
      async16(Vb + (size_t)(8 * i + srow8) * T_ + p0 + schunk * 8,
              (char*)&lV[0][0] + i * 1024);
    }
  }

  const int swz = (l31 & 7);

  for (int kt = 0; kt < nkt_blk; ++kt) {
    const int cur = kt & 1;
    const int p0 = kt * 64;
    if (kt + 1 < nkt_blk) {
      const int pn = p0 + 64;
#pragma unroll
      for (int j = 0; j < 2; ++j) {
        int i = 2 * wv + j;
        async16(Kb + (size_t)(pn + 8 * i + srow8) * HD + schunk * 8,
                (char*)&lK[cur ^ 1][0] + i * 1024);
        async16(Vb + (size_t)(8 * i + srow8) * T_ + pn + schunk * 8,
                (char*)&lV[cur ^ 1][0] + i * 1024);
      }
      asm volatile("s_waitcnt vmcnt(4)" ::: "memory");
    } else {
      asm volatile("s_waitcnt vmcnt(0)" ::: "memory");
    }
    __syncthreads();

    if (kt <= myKt) {
      const uint16_t* lk = &lK[cur][0];
      const uint16_t* lv = &lV[cur][0];

      f32x16 st[2];
#pragma unroll
      for (int a = 0; a < 2; ++a) {
        short8 kf[4];
#pragma unroll
        for (int kc = 0; kc < 4; ++kc)
          kf[kc] = *(const short8*)&lk[(32 * a + l31) * 64 + (((2 * kc + hi) ^ swz) * 8)];
#pragma unroll
        for (int r = 0; r < 16; ++r) st[a][r] = 0.f;
        __builtin_amdgcn_s_setprio(1);
#pragma unroll
        for (int kc = 0; kc < 4; ++kc)
          st[a] = __builtin_amdgcn_mfma_f32_32x32x16_bf16(kf[kc], qf[kc], st[a], 0, 0, 0);
        __builtin_amdgcn_s_setprio(0);
      }

      if (kt == myKt) {
#pragma unroll
        for (int a = 0; a < 2; ++a) {
          int kbase = p0 + 32 * a + 4 * hi;
#pragma unroll
          for (int r = 0; r < 16; ++r) {
            int key = kbase + (r & 3) + 8 * (r >> 2);
            if (key > qg) st[a][r] = -__builtin_inff();
          }
        }
      }

      float mall = halves_max(tmax32(st[0], st[1]));
      if (__any(mall > mrun + 8.0f)) {
        float mnew = fmaxf(mrun, mall);
        float alpha = __builtin_amdgcn_exp2f(mrun - mnew);
        mrun = mnew;
        lrun *= alpha;
#pragma unroll
        for (int dt = 0; dt < 2; ++dt)
#pragma unroll
          for (int r = 0; r < 16; ++r) ot[dt][r] *= alpha;
      }

#pragma unroll
      for (int a = 0; a < 2; ++a)
#pragma unroll
        for (int r = 0; r < 16; ++r)
          st[a][r] = __builtin_amdgcn_exp2f(st[a][r] - mrun);

      lrun += halves_sum(tsum32(st[0], st[1]));

      short8 pb[4];
#pragma unroll
      for (int kc = 0; kc < 4; ++kc) {
#define PV_(i) ((8 * kc + (i)) < 16 ? st[0][(8 * kc + (i)) & 15] : st[1][(8 * kc + (i)) & 15])
        uint32_t u0 = pkbf(PV_(0), PV_(1));
        uint32_t u1 = pkbf(PV_(2), PV_(3));
        uint32_t u2 = pkbf(PV_(4), PV_(5));
        uint32_t u3 = pkbf(PV_(6), PV_(7));
#undef PV_
        uint32x2 s02 = plswap(u0, u2);
        uint32x2 s13 = plswap(u1, u3);
        union { uint32_t w[4]; short8 s; } pbu;
        pbu.w[0] = s02[0]; pbu.w[1] = s13[0]; pbu.w[2] = s02[1]; pbu.w[3] = s13[1];
        pb[kc] = pbu.s;
      }

#pragma unroll
      for (int dt = 0; dt < 2; ++dt) {
        short8 vf[4];
#pragma unroll
        for (int kc = 0; kc < 4; ++kc)
          vf[kc] = *(const short8*)&lv[(32 * dt + l31) * 64 + (((2 * kc + hi) ^ swz) * 8)];
        __builtin_amdgcn_s_setprio(1);
#pragma unroll
        for (int kc = 0; kc < 4; ++kc)
          ot[dt] = __builtin_amdgcn_mfma_f32_32x32x16_bf16(vf[kc], pb[kc], ot[dt], 0, 0, 0);
        __builtin_amdgcn_s_setprio(0);
      }
    }
    __syncthreads();
  }

  float inv = 1.0f / lrun;
  uint16_t* Yrow = Y + ((size_t)b * T_ + qg) * CDIM + h * HD;
#pragma unroll
  for (int dt = 0; dt < 2; ++dt)
#pragma unroll
    for (int g = 0; g < 4; ++g) {
      int d0 = 32 * dt + 8 * g + 4 * hi;
      ushort4 o4;
      o4.x = f2bf(ot[dt][4 * g + 0] * inv);
      o4.y = f2bf(ot[dt][4 * g + 1] * inv);
      o4.z = f2bf(ot[dt][4 * g + 2] * inv);
      o4.w = f2bf(ot[dt][4 * g + 3] * inv);
      *(ushort4*)(Yrow + d0) = o4;
    }
}

// ---------------- launch ----------------
extern "C" void kernel_launch(void* const* d_in, const int* in_sizes, int n_in,
                              void* d_out, int out_size, void* d_ws, size_t ws_size,
                              hipStream_t stream) {
  const float* x = (const float*)d_in[0];
  const float* wqkv = (const float*)d_in[1];
  const float* wproj = (const float*)d_in[2];
  const float* bproj = (const float*)d_in[3];
  const int* perm = (const int*)d_in[4];
  float* out = (float*)d_out;

  char* ws = (char*)d_ws;
  uint16_t* xb     = (uint16_t*)(ws + 0);          // 16 MB (reused as Y later)
  uint16_t* wqkvb  = (uint16_t*)(ws + 16777216);   // 6 MB
  uint16_t* wprojb = (uint16_t*)(ws + 23068672);   // 2 MB
  uint16_t* Qb     = (uint16_t*)(ws + 25165824);   // 16 MB
  uint16_t* Kb     = (uint16_t*)(ws + 41943040);   // 16 MB
  uint16_t* Vpb    = (uint16_t*)(ws + 58720256);   // 16 MB
  uint16_t* Vtb    = (uint16_t*)(ws + 75497472);   // 16 MB
  uint16_t* Yb     = xb;                           // reuse (x no longer needed)

  cvt_f32_bf16<<<2048, 256, 0, stream>>>(x, xb, MROWS * CDIM);
  cvt_f32_bf16<<<1024, 256, 0, stream>>>(wqkv, wqkvb, 3 * CDIM * CDIM);
  cvt_f32_bf16<<<512, 256, 0, stream>>>(wproj, wprojb, CDIM * CDIM);

  gemm256v2<<<384, 512, 0, stream>>>(xb, wqkvb, Qb, Kb, Vpb, perm);
  transpose_v<<<dim3(32, 64), 256, 0, stream>>>(Vpb, Vtb);
  attn_kernel<<<dim3(64, 16), 256, 0, stream>>>(Qb, Kb, Vtb, Yb);
  gemm_bt<<<dim3(64, 8), 256, 0, stream>>>(Yb, wprojb, out, bproj, CDIM);
}

// Round 9
// 170.757 us; speedup vs baseline: 1.2903x; 1.2903x over previous
//
#include <hip/hip_runtime.h>
#include <stdint.h>

// Problem constants
#define T_   2048
#define NH   16
#define HD   64
#define NBH  64     // B*H
#define CDIM 1024
#define MROWS 8192  // B*T

typedef __attribute__((ext_vector_type(8))) short short8;
typedef __attribute__((ext_vector_type(4))) float f32x4;
typedef __attribute__((ext_vector_type(16))) float f32x16;
typedef __attribute__((ext_vector_type(2))) unsigned int uint32x2;

#define LOG2E 1.44269504088896340736f

static __device__ __forceinline__ uint16_t f2bf(float f) {
  uint32_t u = __float_as_uint(f);
  return (uint16_t)((u + 0x7FFFu + ((u >> 16) & 1u)) >> 16);
}

static __device__ __forceinline__ void async16(const void* g, void* l) {
  __builtin_amdgcn_global_load_lds(
      (const __attribute__((address_space(1))) uint32_t*)g,
      (__attribute__((address_space(3))) uint32_t*)l, 16, 0, 0);
}

// permlane32_swap builtin: returns {vdst_new, vsrc_new}
static __device__ __forceinline__ uint32x2 plswap(uint32_t a, uint32_t b) {
  return __builtin_amdgcn_permlane32_swap(a, b, false, false);
}
static __device__ __forceinline__ float halves_max(float x) {
  uint32x2 r = plswap(__float_as_uint(x), __float_as_uint(x));
  return fmaxf(__uint_as_float(r[0]), __uint_as_float(r[1]));
}
static __device__ __forceinline__ float halves_sum(float x) {
  uint32x2 r = plswap(__float_as_uint(x), __float_as_uint(x));
  return __uint_as_float(r[0]) + __uint_as_float(r[1]);
}
static __device__ __forceinline__ uint32_t pkbf(float lo, float hi) {
  uint32_t r;
  asm("v_cvt_pk_bf16_f32 %0, %1, %2" : "=v"(r) : "v"(lo), "v"(hi));
  return r;
}
static __device__ __forceinline__ float tmax32(const f32x16& a, const f32x16& b) {
  float t[16];
#pragma unroll
  for (int r = 0; r < 16; ++r) t[r] = fmaxf(a[r], b[r]);
#pragma unroll
  for (int s = 8; s >= 1; s >>= 1)
#pragma unroll
    for (int r = 0; r < s; ++r) t[r] = fmaxf(t[r], t[r + s]);
  return t[0];
}
static __device__ __forceinline__ float tsum32(const f32x16& a, const f32x16& b) {
  float t[16];
#pragma unroll
  for (int r = 0; r < 16; ++r) t[r] = a[r] + b[r];
#pragma unroll
  for (int s = 8; s >= 1; s >>= 1)
#pragma unroll
    for (int r = 0; r < s; ++r) t[r] += t[r + s];
  return t[0];
}

// ---------------- fused fp32 -> bf16 convert (x, w_qkv, w_proj in one) ------
__global__ __launch_bounds__(256) void cvt3_f32_bf16(
    const float* __restrict__ a, uint16_t* __restrict__ oa, int na,
    const float* __restrict__ b, uint16_t* __restrict__ ob, int nb,
    const float* __restrict__ c, uint16_t* __restrict__ oc, int nc) {
  const int stride = gridDim.x * 256 * 4;
  for (int i = (blockIdx.x * 256 + threadIdx.x) * 4; i < na; i += stride) {
    float4 v = *(const float4*)(a + i);
    ushort4 o; o.x = f2bf(v.x); o.y = f2bf(v.y); o.z = f2bf(v.z); o.w = f2bf(v.w);
    *(ushort4*)(oa + i) = o;
  }
  for (int i = (blockIdx.x * 256 + threadIdx.x) * 4; i < nb; i += stride) {
    float4 v = *(const float4*)(b + i);
    ushort4 o; o.x = f2bf(v.x); o.y = f2bf(v.y); o.z = f2bf(v.z); o.w = f2bf(v.w);
    *(ushort4*)(ob + i) = o;
  }
  for (int i = (blockIdx.x * 256 + threadIdx.x) * 4; i < nc; i += stride) {
    float4 v = *(const float4*)(c + i);
    ushort4 o; o.x = f2bf(v.x); o.y = f2bf(v.y); o.z = f2bf(v.z); o.w = f2bf(v.w);
    *(ushort4*)(oc + i) = o;
  }
}

// ---------------- GEMM: C[M,N] = A[M,K] * Bt[N,K]^T ----------------
// 128x128 tile, BK=32, 4 waves (2x2 of 64x64), 16x16x32 bf16 MFMA.
// 16KB LDS + 76 VGPR -> ~6 blocks/CU: inter-block overlap hides the per-tile
// vmcnt(0) drain (m114). R9: both-sides XOR bank swizzle — source 16B-chunk
// pre-swizzled csrc = (l&3)^((l>>3)&3) (LDS dest stays linear), read slot
// = gq ^ ((lc>>1)&3). Verified conflict-free: each 8-lane octet covers all
// 32 banks (profiled 0 conflicts in R8's v2 with identical math).
// MODE 0: Cout fp32 = acc + bias[col]   (N = row stride)
// MODE 1: QKV scatter epilogue (N total = 3072; col>>10 selects Q/K/V)
template <int MODE>
__global__ __launch_bounds__(256) void gemm_bt(
    const uint16_t* __restrict__ A, const uint16_t* __restrict__ Bt,
    float* __restrict__ Cout, const float* __restrict__ bias,
    uint16_t* __restrict__ Qo, uint16_t* __restrict__ Ko, uint16_t* __restrict__ Vo,
    const int* __restrict__ perm, int N) {
  __shared__ uint16_t lA[128 * 32];
  __shared__ uint16_t lB[128 * 32];

  const int t = threadIdx.x;
  const int lane = t & 63, wv = t >> 6;
  const int gq = lane >> 4, lc = lane & 15;
  const int mbase = blockIdx.x * 128;
  const int nbase = blockIdx.y * 128;
  const int wr = (wv >> 1) * 64, wc = (wv & 1) * 64;

  f32x4 acc[4][4];
#pragma unroll
  for (int i = 0; i < 4; ++i)
#pragma unroll
    for (int j = 0; j < 4; ++j) acc[i][j] = (f32x4){0.f, 0.f, 0.f, 0.f};

  const int srow = t >> 2;                              // 0..63 (per issue)
  const int scb  = (((t & 3) ^ ((t >> 3) & 3)) * 16);   // pre-swizzled source chunk (bytes)
  const int rxs  = (lc >> 1) & 3;                       // read-side slot XOR

  for (int kt = 0; kt < 32; ++kt) {
    const char* baseA = (const char*)A + ((size_t)mbase * CDIM + kt * 32) * 2;
    const char* baseB = (const char*)Bt + ((size_t)nbase * CDIM + kt * 32) * 2;
#pragma unroll
    for (int j = 0; j < 2; ++j) {
      int row = j * 64 + srow;
      async16(baseA + (size_t)row * (CDIM * 2) + scb, (char*)lA + j * 4096 + wv * 1024);
    }
#pragma unroll
    for (int j = 0; j < 2; ++j) {
      int row = j * 64 + srow;
      async16(baseB + (size_t)row * (CDIM * 2) + scb, (char*)lB + j * 4096 + wv * 1024);
    }
    asm volatile("s_waitcnt vmcnt(0)" ::: "memory");
    __syncthreads();

    short8 af[4], bfr[4];
#pragma unroll
    for (int mi = 0; mi < 4; ++mi)
      af[mi] = *(const short8*)&lA[(wr + mi * 16 + lc) * 32 + ((gq ^ rxs) * 8)];
#pragma unroll
    for (int ni = 0; ni < 4; ++ni)
      bfr[ni] = *(const short8*)&lB[(wc + ni * 16 + lc) * 32 + ((gq ^ rxs) * 8)];
#pragma unroll
    for (int mi = 0; mi < 4; ++mi)
#pragma unroll
      for (int ni = 0; ni < 4; ++ni)
        acc[mi][ni] = __builtin_amdgcn_mfma_f32_16x16x32_bf16(af[mi], bfr[ni], acc[mi][ni], 0, 0, 0);
    __syncthreads();
  }

  if (MODE == 0) {
#pragma unroll
    for (int mi = 0; mi < 4; ++mi) {
      int row = mbase + wr + mi * 16 + 4 * gq;
#pragma unroll
      for (int ni = 0; ni < 4; ++ni) {
        int col = nbase + wc + ni * 16 + lc;
        float bv = bias[col];
#pragma unroll
        for (int r = 0; r < 4; ++r)
          Cout[(size_t)(row + r) * N + col] = acc[mi][ni][r] + bv;
      }
    }
  } else {
#pragma unroll
    for (int mi = 0; mi < 4; ++mi) {
#pragma unroll
      for (int r = 0; r < 4; ++r) {
        int m = mbase + wr + mi * 16 + 4 * gq + r;
        int b = m >> 11, s = m & 2047;
        int p = perm[s];
#pragma unroll
        for (int ni = 0; ni < 4; ++ni) {
          int col = nbase + wc + ni * 16 + lc;
          int typ = col >> 10, cc = col & 1023;
          int h = cc >> 6, d = cc & 63;
          int bh = b * 16 + h;
          float v = acc[mi][ni][r];
          if (typ == 0)
            Qo[((size_t)bh * T_ + s) * HD + d] = f2bf(v * (0.125f * LOG2E));  // fold 1/sqrt(D), log2(e)
          else if (typ == 1)
            Ko[((size_t)bh * T_ + p) * HD + d] = f2bf(v);
          else
            Vo[((size_t)bh * T_ + p) * HD + d] = f2bf(v);
        }
      }
    }
  }
}

// ---------------- V transpose: [bh][p][d] -> [bh][d][p] ----------------
__global__ __launch_bounds__(256) void transpose_v(const uint16_t* __restrict__ Vp,
                                                   uint16_t* __restrict__ Vt) {
  __shared__ uint16_t tile[64][72];
  const int pb = blockIdx.x * 64;
  const int bh = blockIdx.y;
  const int t = threadIdx.x;
  const uint16_t* src = Vp + (size_t)bh * T_ * HD + (size_t)pb * HD;
#pragma unroll
  for (int it = 0; it < 2; ++it) {
    int lin = it * 256 + t;
    int row = lin >> 3, col = (lin & 7) * 8;
    short8 v = *(const short8*)(src + row * HD + col);
    *(short8*)&tile[row][col] = v;
  }
  __syncthreads();
  uint16_t* dst = Vt + (size_t)bh * HD * T_;
#pragma unroll
  for (int it = 0; it < 2; ++it) {
    int lin = it * 256 + t;
    int d = lin >> 3, ps = (lin & 7) * 8;
    short8 v;
#pragma unroll
    for (int j = 0; j < 8; ++j) v[j] = (short)tile[ps + j][d];
    *(short8*)(dst + (size_t)d * T_ + pb + ps) = v;
  }
}

// ---------------- causal flash attention, swapped-operand 32x32 ----------------
// LDS-staged K/V tiles (64-key, double-buffered, counted vmcnt(4)), fragments
// via swizzled ds_read_b128 (chunk ^= row&7 both sides). Swapped QK^T
// (St = mfma(K,Q)), tree reductions, defer-max (THR=8), cvt_pk+permlane P
// redistribution, O^T accumulation. Q pre-scaled by (1/8)*log2(e).
__global__ __launch_bounds__(256, 4) void attn_kernel(
    const uint16_t* __restrict__ Q, const uint16_t* __restrict__ Kp,
    const uint16_t* __restrict__ Vt, uint16_t* __restrict__ Y) {
  __shared__ __attribute__((aligned(16))) uint16_t lK[2][64 * 64];
  __shared__ __attribute__((aligned(16))) uint16_t lV[2][64 * 64];

  const int bh = blockIdx.x;
  const int b = bh >> 4, h = bh & 15;
  const int qb = (gridDim.y - 1 - blockIdx.y) * 128;  // heavy blocks first
  const int t = threadIdx.x;
  const int lane = t & 63, wv = t >> 6;
  const int l31 = lane & 31, hi = lane >> 5;
  const int qw = qb + 32 * wv;
  const int qg = qw + l31;

  const uint16_t* Qb = Q + ((size_t)bh * T_ + qw) * HD;
  const uint16_t* Kb = Kp + (size_t)bh * T_ * HD;
  const uint16_t* Vb = Vt + (size_t)bh * HD * T_;

  const int srow8 = lane >> 3;               // 0..7
  const int schunk = (lane & 7) ^ srow8;     // swizzled source chunk (16B units)

  short8 qf[4];
#pragma unroll
  for (int kc = 0; kc < 4; ++kc)
    qf[kc] = *(const short8*)(Qb + (size_t)l31 * HD + 16 * kc + 8 * hi);

  f32x16 ot[2];
#pragma unroll
  for (int dt = 0; dt < 2; ++dt)
#pragma unroll
    for (int r = 0; r < 16; ++r) ot[dt][r] = 0.f;
  float mrun = -__builtin_inff();
  float lrun = 0.f;

  const int nkt_blk = (qb >> 6) + 2;
  const int myKt = qw >> 6;

  {
    const int p0 = 0;
#pragma unroll
    for (int j = 0; j < 2; ++j) {
      int i = 2 * wv + j;
      async16(Kb + (size_t)(p0 + 8 * i + srow8) * HD + schunk * 8,
              (char*)&lK[0][0] + i * 1024);
      async16(Vb + (size_t)(8 * i + srow8) * T_ + p0 + schunk * 8,
              (char*)&lV[0][0] + i * 1024);
    }
  }

  const int swz = (l31 & 7);

  for (int kt = 0; kt < nkt_blk; ++kt) {
    const int cur = kt & 1;
    const int p0 = kt * 64;
    if (kt + 1 < nkt_blk) {
      const int pn = p0 + 64;
#pragma unroll
      for (int j = 0; j < 2; ++j) {
        int i = 2 * wv + j;
        async16(Kb + (size_t)(pn + 8 * i + srow8) * HD + schunk * 8,
                (char*)&lK[cur ^ 1][0] + i * 1024);
        async16(Vb + (size_t)(8 * i + srow8) * T_ + pn + schunk * 8,
                (char*)&lV[cur ^ 1][0] + i * 1024);
      }
      asm volatile("s_waitcnt vmcnt(4)" ::: "memory");
    } else {
      asm volatile("s_waitcnt vmcnt(0)" ::: "memory");
    }
    __syncthreads();

    if (kt <= myKt) {
      const uint16_t* lk = &lK[cur][0];
      const uint16_t* lv = &lV[cur][0];

      f32x16 st[2];
#pragma unroll
      for (int a = 0; a < 2; ++a) {
        short8 kf[4];
#pragma unroll
        for (int kc = 0; kc < 4; ++kc)
          kf[kc] = *(const short8*)&lk[(32 * a + l31) * 64 + (((2 * kc + hi) ^ swz) * 8)];
#pragma unroll
        for (int r = 0; r < 16; ++r) st[a][r] = 0.f;
        __builtin_amdgcn_s_setprio(1);
#pragma unroll
        for (int kc = 0; kc < 4; ++kc)
          st[a] = __builtin_amdgcn_mfma_f32_32x32x16_bf16(kf[kc], qf[kc], st[a], 0, 0, 0);
        __builtin_amdgcn_s_setprio(0);
      }

      if (kt == myKt) {
#pragma unroll
        for (int a = 0; a < 2; ++a) {
          int kbase = p0 + 32 * a + 4 * hi;
#pragma unroll
          for (int r = 0; r < 16; ++r) {
            int key = kbase + (r & 3) + 8 * (r >> 2);
            if (key > qg) st[a][r] = -__builtin_inff();
          }
        }
      }

      float mall = halves_max(tmax32(st[0], st[1]));
      if (__any(mall > mrun + 8.0f)) {
        float mnew = fmaxf(mrun, mall);
        float alpha = __builtin_amdgcn_exp2f(mrun - mnew);
        mrun = mnew;
        lrun *= alpha;
#pragma unroll
        for (int dt = 0; dt < 2; ++dt)
#pragma unroll
          for (int r = 0; r < 16; ++r) ot[dt][r] *= alpha;
      }

#pragma unroll
      for (int a = 0; a < 2; ++a)
#pragma unroll
        for (int r = 0; r < 16; ++r)
          st[a][r] = __builtin_amdgcn_exp2f(st[a][r] - mrun);

      lrun += halves_sum(tsum32(st[0], st[1]));

      short8 pb[4];
#pragma unroll
      for (int kc = 0; kc < 4; ++kc) {
#define PV_(i) ((8 * kc + (i)) < 16 ? st[0][(8 * kc + (i)) & 15] : st[1][(8 * kc + (i)) & 15])
        uint32_t u0 = pkbf(PV_(0), PV_(1));
        uint32_t u1 = pkbf(PV_(2), PV_(3));
        uint32_t u2 = pkbf(PV_(4), PV_(5));
        uint32_t u3 = pkbf(PV_(6), PV_(7));
#undef PV_
        uint32x2 s02 = plswap(u0, u2);
        uint32x2 s13 = plswap(u1, u3);
        union { uint32_t w[4]; short8 s; } pbu;
        pbu.w[0] = s02[0]; pbu.w[1] = s13[0]; pbu.w[2] = s02[1]; pbu.w[3] = s13[1];
        pb[kc] = pbu.s;
      }

#pragma unroll
      for (int dt = 0; dt < 2; ++dt) {
        short8 vf[4];
#pragma unroll
        for (int kc = 0; kc < 4; ++kc)
          vf[kc] = *(const short8*)&lv[(32 * dt + l31) * 64 + (((2 * kc + hi) ^ swz) * 8)];
        __builtin_amdgcn_s_setprio(1);
#pragma unroll
        for (int kc = 0; kc < 4; ++kc)
          ot[dt] = __builtin_amdgcn_mfma_f32_32x32x16_bf16(vf[kc], pb[kc], ot[dt], 0, 0, 0);
        __builtin_amdgcn_s_setprio(0);
      }
    }
    __syncthreads();
  }

  float inv = 1.0f / lrun;
  uint16_t* Yrow = Y + ((size_t)b * T_ + qg) * CDIM + h * HD;
#pragma unroll
  for (int dt = 0; dt < 2; ++dt)
#pragma unroll
    for (int g = 0; g < 4; ++g) {
      int d0 = 32 * dt + 8 * g + 4 * hi;
      ushort4 o4;
      o4.x = f2bf(ot[dt][4 * g + 0] * inv);
      o4.y = f2bf(ot[dt][4 * g + 1] * inv);
      o4.z = f2bf(ot[dt][4 * g + 2] * inv);
      o4.w = f2bf(ot[dt][4 * g + 3] * inv);
      *(ushort4*)(Yrow + d0) = o4;
    }
}

// ---------------- launch ----------------
extern "C" void kernel_launch(void* const* d_in, const int* in_sizes, int n_in,
                              void* d_out, int out_size, void* d_ws, size_t ws_size,
                              hipStream_t stream) {
  const float* x = (const float*)d_in[0];
  const float* wqkv = (const float*)d_in[1];
  const float* wproj = (const float*)d_in[2];
  const float* bproj = (const float*)d_in[3];
  const int* perm = (const int*)d_in[4];
  float* out = (float*)d_out;

  char* ws = (char*)d_ws;
  uint16_t* xb     = (uint16_t*)(ws + 0);          // 16 MB (reused as Y later)
  uint16_t* wqkvb  = (uint16_t*)(ws + 16777216);   // 6 MB
  uint16_t* wprojb = (uint16_t*)(ws + 23068672);   // 2 MB
  uint16_t* Qb     = (uint16_t*)(ws + 25165824);   // 16 MB
  uint16_t* Kb     = (uint16_t*)(ws + 41943040);   // 16 MB
  uint16_t* Vpb    = (uint16_t*)(ws + 58720256);   // 16 MB
  uint16_t* Vtb    = (uint16_t*)(ws + 75497472);   // 16 MB
  uint16_t* Yb     = xb;                           // reuse (x no longer needed)

  cvt3_f32_bf16<<<2048, 256, 0, stream>>>(x, xb, MROWS * CDIM,
                                          wqkv, wqkvb, 3 * CDIM * CDIM,
                                          wproj, wprojb, CDIM * CDIM);

  gemm_bt<1><<<dim3(64, 24), 256, 0, stream>>>(xb, wqkvb, nullptr, nullptr,
                                               Qb, Kb, Vpb, perm, 3072);
  transpose_v<<<dim3(32, 64), 256, 0, stream>>>(Vpb, Vtb);
  attn_kernel<<<dim3(64, 16), 256, 0, stream>>>(Qb, Kb, Vtb, Yb);
  gemm_bt<0><<<dim3(64, 8), 256, 0, stream>>>(Yb, wprojb, out, bproj,
                                              nullptr, nullptr, nullptr, nullptr, CDIM);
}

// Round 10
// 165.678 us; speedup vs baseline: 1.3298x; 1.0307x over previous
//
#include <hip/hip_runtime.h>
#include <stdint.h>

// Problem constants
#define T_   2048
#define NH   16
#define HD   64
#define NBH  64     // B*H
#define CDIM 1024
#define MROWS 8192  // B*T

typedef __attribute__((ext_vector_type(8))) short short8;
typedef __attribute__((ext_vector_type(4))) float f32x4;
typedef __attribute__((ext_vector_type(16))) float f32x16;
typedef __attribute__((ext_vector_type(2))) unsigned int uint32x2;

#define LOG2E 1.44269504088896340736f

static __device__ __forceinline__ uint16_t f2bf(float f) {
  uint32_t u = __float_as_uint(f);
  return (uint16_t)((u + 0x7FFFu + ((u >> 16) & 1u)) >> 16);
}

static __device__ __forceinline__ void async16(const void* g, void* l) {
  __builtin_amdgcn_global_load_lds(
      (const __attribute__((address_space(1))) uint32_t*)g,
      (__attribute__((address_space(3))) uint32_t*)l, 16, 0, 0);
}

// permlane32_swap builtin: returns {vdst_new, vsrc_new}
static __device__ __forceinline__ uint32x2 plswap(uint32_t a, uint32_t b) {
  return __builtin_amdgcn_permlane32_swap(a, b, false, false);
}
static __device__ __forceinline__ float halves_max(float x) {
  uint32x2 r = plswap(__float_as_uint(x), __float_as_uint(x));
  return fmaxf(__uint_as_float(r[0]), __uint_as_float(r[1]));
}
static __device__ __forceinline__ float halves_sum(float x) {
  uint32x2 r = plswap(__float_as_uint(x), __float_as_uint(x));
  return __uint_as_float(r[0]) + __uint_as_float(r[1]);
}
static __device__ __forceinline__ uint32_t pkbf(float lo, float hi) {
  uint32_t r;
  asm("v_cvt_pk_bf16_f32 %0, %1, %2" : "=v"(r) : "v"(lo), "v"(hi));
  return r;
}
static __device__ __forceinline__ float tmax32(const f32x16& a, const f32x16& b) {
  float t[16];
#pragma unroll
  for (int r = 0; r < 16; ++r) t[r] = fmaxf(a[r], b[r]);
#pragma unroll
  for (int s = 8; s >= 1; s >>= 1)
#pragma unroll
    for (int r = 0; r < s; ++r) t[r] = fmaxf(t[r], t[r + s]);
  return t[0];
}
static __device__ __forceinline__ float tsum32(const f32x16& a, const f32x16& b) {
  float t[16];
#pragma unroll
  for (int r = 0; r < 16; ++r) t[r] = a[r] + b[r];
#pragma unroll
  for (int s = 8; s >= 1; s >>= 1)
#pragma unroll
    for (int r = 0; r < s; ++r) t[r] += t[r + s];
  return t[0];
}

// ---------------- fused fp32 -> bf16 convert (x, w_qkv, w_proj in one) ------
__global__ __launch_bounds__(256) void cvt3_f32_bf16(
    const float* __restrict__ a, uint16_t* __restrict__ oa, int na,
    const float* __restrict__ b, uint16_t* __restrict__ ob, int nb,
    const float* __restrict__ c, uint16_t* __restrict__ oc, int nc) {
  const int stride = gridDim.x * 256 * 4;
  for (int i = (blockIdx.x * 256 + threadIdx.x) * 4; i < na; i += stride) {
    float4 v = *(const float4*)(a + i);
    ushort4 o; o.x = f2bf(v.x); o.y = f2bf(v.y); o.z = f2bf(v.z); o.w = f2bf(v.w);
    *(ushort4*)(oa + i) = o;
  }
  for (int i = (blockIdx.x * 256 + threadIdx.x) * 4; i < nb; i += stride) {
    float4 v = *(const float4*)(b + i);
    ushort4 o; o.x = f2bf(v.x); o.y = f2bf(v.y); o.z = f2bf(v.z); o.w = f2bf(v.w);
    *(ushort4*)(ob + i) = o;
  }
  for (int i = (blockIdx.x * 256 + threadIdx.x) * 4; i < nc; i += stride) {
    float4 v = *(const float4*)(c + i);
    ushort4 o; o.x = f2bf(v.x); o.y = f2bf(v.y); o.z = f2bf(v.z); o.w = f2bf(v.w);
    *(ushort4*)(oc + i) = o;
  }
}

// ---------------- GEMM: C[M,N] = A[M,K] * Bt[N,K]^T ----------------
// 128x128 tile, BK=32, 4 waves (2x2 of 64x64), 16x16x32 bf16 MFMA.
// K-loop identical to R9 (0 bank conflicts, 6 blocks/CU).
// MODE 0: Cout fp32 = acc + bias[col] direct (already coalesced 64B segs).
// MODE 1 (QKV): two-pass LDS-repack epilogue — acc -> bf16 LDS [128][64]
// (chunk XOR ((row>>2)&3)<<1, conflict-free b16 writes + b128 reads), then
// 8 coalesced 16B stores/thread (vs 64 scattered 2B): Q pre-scaled at LDS
// write, perm applied at readback.
template <int MODE>
__global__ __launch_bounds__(256) void gemm_bt(
    const uint16_t* __restrict__ A, const uint16_t* __restrict__ Bt,
    float* __restrict__ Cout, const float* __restrict__ bias,
    uint16_t* __restrict__ Qo, uint16_t* __restrict__ Ko, uint16_t* __restrict__ Vo,
    const int* __restrict__ perm, int N) {
  __shared__ __attribute__((aligned(16))) uint16_t lds[8192];  // 16KB
  uint16_t* lA = lds;           // [128*32]
  uint16_t* lB = lds + 4096;    // [128*32]

  const int t = threadIdx.x;
  const int lane = t & 63, wv = t >> 6;
  const int gq = lane >> 4, lc = lane & 15;
  const int mbase = blockIdx.x * 128;
  const int nbase = blockIdx.y * 128;
  const int wr = (wv >> 1) * 64, wc = (wv & 1) * 64;

  f32x4 acc[4][4];
#pragma unroll
  for (int i = 0; i < 4; ++i)
#pragma unroll
    for (int j = 0; j < 4; ++j) acc[i][j] = (f32x4){0.f, 0.f, 0.f, 0.f};

  const int srow = t >> 2;                              // 0..63 (per issue)
  const int scb  = (((t & 3) ^ ((t >> 3) & 3)) * 16);   // pre-swizzled source chunk (bytes)
  const int rxs  = (lc >> 1) & 3;                       // read-side slot XOR

  for (int kt = 0; kt < 32; ++kt) {
    const char* baseA = (const char*)A + ((size_t)mbase * CDIM + kt * 32) * 2;
    const char* baseB = (const char*)Bt + ((size_t)nbase * CDIM + kt * 32) * 2;
#pragma unroll
    for (int j = 0; j < 2; ++j) {
      int row = j * 64 + srow;
      async16(baseA + (size_t)row * (CDIM * 2) + scb, (char*)lA + j * 4096 + wv * 1024);
    }
#pragma unroll
    for (int j = 0; j < 2; ++j) {
      int row = j * 64 + srow;
      async16(baseB + (size_t)row * (CDIM * 2) + scb, (char*)lB + j * 4096 + wv * 1024);
    }
    asm volatile("s_waitcnt vmcnt(0)" ::: "memory");
    __syncthreads();

    short8 af[4], bfr[4];
#pragma unroll
    for (int mi = 0; mi < 4; ++mi)
      af[mi] = *(const short8*)&lA[(wr + mi * 16 + lc) * 32 + ((gq ^ rxs) * 8)];
#pragma unroll
    for (int ni = 0; ni < 4; ++ni)
      bfr[ni] = *(const short8*)&lB[(wc + ni * 16 + lc) * 32 + ((gq ^ rxs) * 8)];
#pragma unroll
    for (int mi = 0; mi < 4; ++mi)
#pragma unroll
      for (int ni = 0; ni < 4; ++ni)
        acc[mi][ni] = __builtin_amdgcn_mfma_f32_16x16x32_bf16(af[mi], bfr[ni], acc[mi][ni], 0, 0, 0);
    __syncthreads();
  }

  if (MODE == 0) {
#pragma unroll
    for (int mi = 0; mi < 4; ++mi) {
      int row = mbase + wr + mi * 16 + 4 * gq;
#pragma unroll
      for (int ni = 0; ni < 4; ++ni) {
        int col = nbase + wc + ni * 16 + lc;
        float bv = bias[col];
#pragma unroll
        for (int r = 0; r < 4; ++r)
          Cout[(size_t)(row + r) * N + col] = acc[mi][ni][r] + bv;
      }
    }
  } else {
    // ---- two-pass LDS-repack scatter epilogue ----
    const int wcw = wv & 1;  // which 64-col half this wave owns
    for (int pass = 0; pass < 2; ++pass) {
      // write phase: ni in {2p, 2p+1} -> LDS [row 0..127][c64 0..63] bf16
#pragma unroll
      for (int mi = 0; mi < 4; ++mi) {
#pragma unroll
        for (int nj = 0; nj < 2; ++nj) {
          int ni = 2 * pass + nj;
          int colg = nbase + wc + ni * 16 + lc;
          bool isQ = (colg < 1024);
          int c64 = wcw * 32 + nj * 16 + lc;
          int within = c64 & 7;
#pragma unroll
          for (int r = 0; r < 4; ++r) {
            int row = wr + mi * 16 + 4 * gq + r;         // 0..127
            int swz = ((row >> 2) & 3) << 1;
            int ch = (c64 >> 3) ^ swz;
            float v = acc[mi][ni][r];
            if (isQ) v *= (0.125f * LOG2E);
            lds[row * 64 + ch * 8 + within] = f2bf(v);
          }
        }
      }
      __syncthreads();
      // read+store phase: 4 coalesced 16B stores per thread
#pragma unroll
      for (int k = 0; k < 4; ++k) {
        int v = 256 * k + t;          // 0..1023
        int row = v >> 3;             // 0..127
        int ch = v & 7;
        int swz = ((row >> 2) & 3) << 1;
        short8 val = *(const short8*)&lds[row * 64 + ((ch ^ swz) * 8)];
        int m = mbase + row;
        int b = m >> 11, s = m & 2047;
        int p = perm[s];
        int colg = nbase + (ch >= 4 ? 64 : 0) + 32 * pass + (ch & 3) * 8;
        int typ = colg >> 10, cc = colg & 1023;
        int h = cc >> 6, d0 = cc & 63;
        int bh = b * 16 + h;
        if (typ == 0)
          *(short8*)(Qo + ((size_t)bh * T_ + s) * HD + d0) = val;
        else if (typ == 1)
          *(short8*)(Ko + ((size_t)bh * T_ + p) * HD + d0) = val;
        else
          *(short8*)(Vo + ((size_t)bh * T_ + p) * HD + d0) = val;
      }
      __syncthreads();
    }
  }
}

// ---------------- V transpose: [bh][p][d] -> [bh][d][p] ----------------
__global__ __launch_bounds__(256) void transpose_v(const uint16_t* __restrict__ Vp,
                                                   uint16_t* __restrict__ Vt) {
  __shared__ uint16_t tile[64][72];
  const int pb = blockIdx.x * 64;
  const int bh = blockIdx.y;
  const int t = threadIdx.x;
  const uint16_t* src = Vp + (size_t)bh * T_ * HD + (size_t)pb * HD;
#pragma unroll
  for (int it = 0; it < 2; ++it) {
    int lin = it * 256 + t;
    int row = lin >> 3, col = (lin & 7) * 8;
    short8 v = *(const short8*)(src + row * HD + col);
    *(short8*)&tile[row][col] = v;
  }
  __syncthreads();
  uint16_t* dst = Vt + (size_t)bh * HD * T_;
#pragma unroll
  for (int it = 0; it < 2; ++it) {
    int lin = it * 256 + t;
    int d = lin >> 3, ps = (lin & 7) * 8;
    short8 v;
#pragma unroll
    for (int j = 0; j < 8; ++j) v[j] = (short)tile[ps + j][d];
    *(short8*)(dst + (size_t)d * T_ + pb + ps) = v;
  }
}

// ---------------- causal flash attention, swapped-operand 32x32 ----------------
// LDS-staged K/V tiles (64-key, double-buffered, counted vmcnt(4)), fragments
// via swizzled ds_read_b128 (chunk ^= row&7 both sides). Swapped QK^T
// (St = mfma(K,Q)), tree reductions, defer-max (THR=8), cvt_pk+permlane P
// redistribution, O^T accumulation. Q pre-scaled by (1/8)*log2(e).
__global__ __launch_bounds__(256, 4) void attn_kernel(
    const uint16_t* __restrict__ Q, const uint16_t* __restrict__ Kp,
    const uint16_t* __restrict__ Vt, uint16_t* __restrict__ Y) {
  __shared__ __attribute__((aligned(16))) uint16_t lK[2][64 * 64];
  __shared__ __attribute__((aligned(16))) uint16_t lV[2][64 * 64];

  const int bh = blockIdx.x;
  const int b = bh >> 4, h = bh & 15;
  const int qb = (gridDim.y - 1 - blockIdx.y) * 128;  // heavy blocks first
  const int t = threadIdx.x;
  const int lane = t & 63, wv = t >> 6;
  const int l31 = lane & 31, hi = lane >> 5;
  const int qw = qb + 32 * wv;
  const int qg = qw + l31;

  const uint16_t* Qb = Q + ((size_t)bh * T_ + qw) * HD;
  const uint16_t* Kb = Kp + (size_t)bh * T_ * HD;
  const uint16_t* Vb = Vt + (size_t)bh * HD * T_;

  const int srow8 = lane >> 3;               // 0..7
  const int schunk = (lane & 7) ^ srow8;     // swizzled source chunk (16B units)

  short8 qf[4];
#pragma unroll
  for (int kc = 0; kc < 4; ++kc)
    qf[kc] = *(const short8*)(Qb + (size_t)l31 * HD + 16 * kc + 8 * hi);

  f32x16 ot[2];
#pragma unroll
  for (int dt = 0; dt < 2; ++dt)
#pragma unroll
    for (int r = 0; r < 16; ++r) ot[dt][r] = 0.f;
  float mrun = -__builtin_inff();
  float lrun = 0.f;

  const int nkt_blk = (qb >> 6) + 2;
  const int myKt = qw >> 6;

  {
    const int p0 = 0;
#pragma unroll
    for (int j = 0; j < 2; ++j) {
      int i = 2 * wv + j;
      async16(Kb + (size_t)(p0 + 8 * i + srow8) * HD + schunk * 8,
              (char*)&lK[0][0] + i * 1024);
      async16(Vb + (size_t)(8 * i + srow8) * T_ + p0 + schunk * 8,
              (char*)&lV[0][0] + i * 1024);
    }
  }

  const int swz = (l31 & 7);

  for (int kt = 0; kt < nkt_blk; ++kt) {
    const int cur = kt & 1;
    const int p0 = kt * 64;
    if (kt + 1 < nkt_blk) {
      const int pn = p0 + 64;
#pragma unroll
      for (int j = 0; j < 2; ++j) {
        int i = 2 * wv + j;
        async16(Kb + (size_t)(pn + 8 * i + srow8) * HD + schunk * 8,
                (char*)&lK[cur ^ 1][0] + i * 1024);
        async16(Vb + (size_t)(8 * i + srow8) * T_ + pn + schunk * 8,
                (char*)&lV[cur ^ 1][0] + i * 1024);
      }
      asm volatile("s_waitcnt vmcnt(4)" ::: "memory");
    } else {
      asm volatile("s_waitcnt vmcnt(0)" ::: "memory");
    }
    __syncthreads();

    if (kt <= myKt) {
      const uint16_t* lk = &lK[cur][0];
      const uint16_t* lv = &lV[cur][0];

      f32x16 st[2];
#pragma unroll
      for (int a = 0; a < 2; ++a) {
        short8 kf[4];
#pragma unroll
        for (int kc = 0; kc < 4; ++kc)
          kf[kc] = *(const short8*)&lk[(32 * a + l31) * 64 + (((2 * kc + hi) ^ swz) * 8)];
#pragma unroll
        for (int r = 0; r < 16; ++r) st[a][r] = 0.f;
        __builtin_amdgcn_s_setprio(1);
#pragma unroll
        for (int kc = 0; kc < 4; ++kc)
          st[a] = __builtin_amdgcn_mfma_f32_32x32x16_bf16(kf[kc], qf[kc], st[a], 0, 0, 0);
        __builtin_amdgcn_s_setprio(0);
      }

      if (kt == myKt) {
#pragma unroll
        for (int a = 0; a < 2; ++a) {
          int kbase = p0 + 32 * a + 4 * hi;
#pragma unroll
          for (int r = 0; r < 16; ++r) {
            int key = kbase + (r & 3) + 8 * (r >> 2);
            if (key > qg) st[a][r] = -__builtin_inff();
          }
        }
      }

      float mall = halves_max(tmax32(st[0], st[1]));
      if (__any(mall > mrun + 8.0f)) {
        float mnew = fmaxf(mrun, mall);
        float alpha = __builtin_amdgcn_exp2f(mrun - mnew);
        mrun = mnew;
        lrun *= alpha;
#pragma unroll
        for (int dt = 0; dt < 2; ++dt)
#pragma unroll
          for (int r = 0; r < 16; ++r) ot[dt][r] *= alpha;
      }

#pragma unroll
      for (int a = 0; a < 2; ++a)
#pragma unroll
        for (int r = 0; r < 16; ++r)
          st[a][r] = __builtin_amdgcn_exp2f(st[a][r] - mrun);

      lrun += halves_sum(tsum32(st[0], st[1]));

      short8 pb[4];
#pragma unroll
      for (int kc = 0; kc < 4; ++kc) {
#define PV_(i) ((8 * kc + (i)) < 16 ? st[0][(8 * kc + (i)) & 15] : st[1][(8 * kc + (i)) & 15])
        uint32_t u0 = pkbf(PV_(0), PV_(1));
        uint32_t u1 = pkbf(PV_(2), PV_(3));
        uint32_t u2 = pkbf(PV_(4), PV_(5));
        uint32_t u3 = pkbf(PV_(6), PV_(7));
#undef PV_
        uint32x2 s02 = plswap(u0, u2);
        uint32x2 s13 = plswap(u1, u3);
        union { uint32_t w[4]; short8 s; } pbu;
        pbu.w[0] = s02[0]; pbu.w[1] = s13[0]; pbu.w[2] = s02[1]; pbu.w[3] = s13[1];
        pb[kc] = pbu.s;
      }

#pragma unroll
      for (int dt = 0; dt < 2; ++dt) {
        short8 vf[4];
#pragma unroll
        for (int kc = 0; kc < 4; ++kc)
          vf[kc] = *(const short8*)&lv[(32 * dt + l31) * 64 + (((2 * kc + hi) ^ swz) * 8)];
        __builtin_amdgcn_s_setprio(1);
#pragma unroll
        for (int kc = 0; kc < 4; ++kc)
          ot[dt] = __builtin_amdgcn_mfma_f32_32x32x16_bf16(vf[kc], pb[kc], ot[dt], 0, 0, 0);
        __builtin_amdgcn_s_setprio(0);
      }
    }
    __syncthreads();
  }

  float inv = 1.0f / lrun;
  uint16_t* Yrow = Y + ((size_t)b * T_ + qg) * CDIM + h * HD;
#pragma unroll
  for (int dt = 0; dt < 2; ++dt)
#pragma unroll
    for (int g = 0; g < 4; ++g) {
      int d0 = 32 * dt + 8 * g + 4 * hi;
      ushort4 o4;
      o4.x = f2bf(ot[dt][4 * g + 0] * inv);
      o4.y = f2bf(ot[dt][4 * g + 1] * inv);
      o4.z = f2bf(ot[dt][4 * g + 2] * inv);
      o4.w = f2bf(ot[dt][4 * g + 3] * inv);
      *(ushort4*)(Yrow + d0) = o4;
    }
}

// ---------------- launch ----------------
extern "C" void kernel_launch(void* const* d_in, const int* in_sizes, int n_in,
                              void* d_out, int out_size, void* d_ws, size_t ws_size,
                              hipStream_t stream) {
  const float* x = (const float*)d_in[0];
  const float* wqkv = (const float*)d_in[1];
  const float* wproj = (const float*)d_in[2];
  const float* bproj = (const float*)d_in[3];
  const int* perm = (const int*)d_in[4];
  float* out = (float*)d_out;

  char* ws = (char*)d_ws;
  uint16_t* xb     = (uint16_t*)(ws + 0);          // 16 MB (reused as Y later)
  uint16_t* wqkvb  = (uint16_t*)(ws + 16777216);   // 6 MB
  uint16_t* wprojb = (uint16_t*)(ws + 23068672);   // 2 MB
  uint16_t* Qb     = (uint16_t*)(ws + 25165824);   // 16 MB
  uint16_t* Kb     = (uint16_t*)(ws + 41943040);   // 16 MB
  uint16_t* Vpb    = (uint16_t*)(ws + 58720256);   // 16 MB
  uint16_t* Vtb    = (uint16_t*)(ws + 75497472);   // 16 MB
  uint16_t* Yb     = xb;                           // reuse (x no longer needed)

  cvt3_f32_bf16<<<2048, 256, 0, stream>>>(x, xb, MROWS * CDIM,
                                          wqkv, wqkvb, 3 * CDIM * CDIM,
                                          wproj, wprojb, CDIM * CDIM);

  gemm_bt<1><<<dim3(64, 24), 256, 0, stream>>>(xb, wqkvb, nullptr, nullptr,
                                               Qb, Kb, Vpb, perm, 3072);
  transpose_v<<<dim3(32, 64), 256, 0, stream>>>(Vpb, Vtb);
  attn_kernel<<<dim3(64, 16), 256, 0, stream>>>(Qb, Kb, Vtb, Yb);
  gemm_bt<0><<<dim3(64, 8), 256, 0, stream>>>(Yb, wprojb, out, bproj,
                                              nullptr, nullptr, nullptr, nullptr, CDIM);
}